// Round 20
// baseline (271.074 us; speedup 1.0000x reference)
//
#include <hip/hip_runtime.h>
#include <hip/hip_fp16.h>

#define HD 4      // heads
#define DD 128    // model dim
#define CC 32     // channels per head
#define SCAN_B 64
#define SCAN_T 256

typedef float  f32x4   __attribute__((ext_vector_type(4)));
typedef short  short8v __attribute__((ext_vector_type(8)));

__device__ __forceinline__ unsigned short f2bf(float x) {
    unsigned u = __float_as_uint(x);
    return (unsigned short)((u + 0x7FFFu + ((u >> 16) & 1u)) >> 16);
}
__device__ __forceinline__ float bf2f(unsigned short h) {
    return __uint_as_float((unsigned)h << 16);
}

// ---------------------------------------------------------------------------
// Precompute per-head weight column-sums and per-relation esum table.
// Multi-block: each block recomputes the tiny WehS (cheap) and handles a
// grid-strided slice of the esum table; block 0 writes Wqh/Wkh.
// ---------------------------------------------------------------------------
__global__ __launch_bounds__(256) void prep_kernel(
    const float* __restrict__ Wq, const float* __restrict__ Wk,
    const float* __restrict__ We, const float* __restrict__ rel,
    float* __restrict__ Wqh, float* __restrict__ Wkh,
    float* __restrict__ esum, int R)
{
    __shared__ float WehS[2][DD][HD];   // 4 KB
    int tid = threadIdx.x;
    for (int i = tid; i < 2 * DD * HD; i += 256) {
        int l = i / (DD * HD);
        int d = (i / HD) % DD;
        int h = i % HD;
        const float* bq = Wq + ((size_t)l * DD + d) * DD + h * CC;
        const float* bk = Wk + ((size_t)l * DD + d) * DD + h * CC;
        const float* be = We + ((size_t)l * DD + d) * DD + h * CC;
        float sq = 0.f, sk = 0.f, se = 0.f;
        for (int c = 0; c < CC; ++c) { sq += bq[c]; sk += bk[c]; se += be[c]; }
        if (blockIdx.x == 0) { Wqh[i] = sq; Wkh[i] = sk; }
        WehS[l][d][h] = se;
    }
    __syncthreads();
    for (int i = blockIdx.x * 256 + tid; i < 2 * R * HD; i += gridDim.x * 256) {
        int l = i / (R * HD);
        int r = (i / HD) % R;
        int h = i % HD;
        const float* rp = rel + (size_t)r * DD;
        float a = 0.f;
        for (int d = 0; d < DD; ++d) a += rp[d] * WehS[l][d][h];
        esum[i] = a;
    }
}

// ---------------------------------------------------------------------------
// Transposed bf16 (hi-only) weight tables.
// ---------------------------------------------------------------------------
__global__ __launch_bounds__(256) void prep_bt(
    const float* __restrict__ pw, const float* __restrict__ Wv,
    unsigned short* __restrict__ btp, unsigned short* __restrict__ btv)
{
    int t = blockIdx.x * 256 + threadIdx.x;
    if (t < 128 * 256) {
        int col = t >> 8, k = t & 255;
        btp[(size_t)col * 256 + k] = f2bf(pw[(size_t)k * DD + col]);
    } else if (t < 128 * 256 + 2 * DD * DD) {
        int u = t - 128 * 256;
        int l = u >> 14;
        int r = u & 16383;
        int col = r >> 7, k = r & 127;
        btv[((size_t)l * DD + col) * DD + k] = f2bf(Wv[((size_t)l * DD + k) * DD + col]);
    }
}

// ---------------------------------------------------------------------------
// Split-bf16 MFMA GEMM, BK=128 chunks, one A-staging phase per chunk.
// B fragments are loaded DIRECTLY from global (table is 32-64 KB, L2/L1
// resident) — no B LDS, 36 KB total => 4 blocks/CU.
// ---------------------------------------------------------------------------
__global__ __launch_bounds__(256) void gemm_mfma(
    const float* __restrict__ A, const int* __restrict__ gather,
    const unsigned short* __restrict__ bth, const float* __restrict__ bias,
    const float* __restrict__ Wqh, const float* __restrict__ Wkh,
    float* __restrict__ Cf, __half* __restrict__ Chf,
    float* __restrict__ qs, float* __restrict__ ks,
    int M, int K)
{
    __shared__ unsigned short AhL[4][4][64][8];   // 16 KB [rowtile][kstep][lane][8]
    __shared__ unsigned short AlL[4][4][64][8];   // 16 KB
    __shared__ float wq[DD * HD], wk[DD * HD];    // 4 KB

    const int tid = threadIdx.x;
    const int wave = tid >> 6, lane = tid & 63;
    const int row0 = blockIdx.x * 64;

    if (qs) {
        for (int i = tid; i < DD * HD; i += 256) { wq[i] = Wqh[i]; wk[i] = Wkh[i]; }
    }

    const int sr = tid >> 2;       // 0..63
    const int sks = tid & 3;       // 0..3
    int arow = row0 + sr; if (arow >= M) arow = M - 1;
    const int ga = gather ? gather[arow] : arow;
    const float* Ap = A + (size_t)ga * K + sks * 32;

    const int fr = lane & 15, fg = lane >> 4;
    const unsigned short* Bb = bth + (size_t)fr * K + fg * 8;  // + (c*16)*K + ch*128 + ksc*32

    f32x4 acc[8] = {};
    float qp[4] = {}, kp[4] = {};

    const int nch = K >> 7;        // 128-wide chunks
    for (int ch = 0; ch < nch; ++ch) {
        float4 a[8];
#pragma unroll
        for (int i = 0; i < 8; ++i) a[i] = *(const float4*)(Ap + ch * 128 + i * 4);

        if (ch) __syncthreads();   // prior chunk's compute done before overwrite

        // ---- write A fragments (hi/lo) ----
        {
            const int rt = sr >> 4, frr = sr & 15;
#pragma unroll
            for (int g = 0; g < 4; ++g) {
                float vv[8] = {a[g*2].x, a[g*2].y, a[g*2].z, a[g*2].w,
                               a[g*2+1].x, a[g*2+1].y, a[g*2+1].z, a[g*2+1].w};
                short8v hv, lv;
#pragma unroll
                for (int j = 0; j < 8; ++j) {
                    unsigned short h = f2bf(vv[j]);
                    hv[j] = (short)h;
                    lv[j] = (short)f2bf(vv[j] - bf2f(h));
                }
                *(short8v*)&AhL[rt][sks][g * 16 + frr][0] = hv;
                *(short8v*)&AlL[rt][sks][g * 16 + frr][0] = lv;
            }
        }
        // ---- fused qk partials from exact fp32 A ----
        if (qs) {
#pragma unroll
            for (int i = 0; i < 8; ++i) {
                const float arr[4] = {a[i].x, a[i].y, a[i].z, a[i].w};
#pragma unroll
                for (int j = 0; j < 4; ++j) {
                    int d = ch * 128 + sks * 32 + i * 4 + j;
                    float4 qw = *(const float4*)&wq[d * HD];
                    float4 kw = *(const float4*)&wk[d * HD];
                    qp[0] += arr[j] * qw.x; qp[1] += arr[j] * qw.y;
                    qp[2] += arr[j] * qw.z; qp[3] += arr[j] * qw.w;
                    kp[0] += arr[j] * kw.x; kp[1] += arr[j] * kw.y;
                    kp[2] += arr[j] * kw.z; kp[3] += arr[j] * kw.w;
                }
            }
        }
        __syncthreads();

        // ---- MFMA: 4 ksteps x 8 col-tiles x 2 passes; B direct from global ----
#pragma unroll
        for (int ksc = 0; ksc < 4; ++ksc) {
            short8v ah = *(const short8v*)&AhL[wave][ksc][lane][0];
            short8v al = *(const short8v*)&AlL[wave][ksc][lane][0];
            short8v bhv[8];
#pragma unroll
            for (int c = 0; c < 8; ++c)
                bhv[c] = *(const short8v*)(Bb + (size_t)(c * 16) * K + ch * 128 + ksc * 32);
#pragma unroll
            for (int c = 0; c < 8; ++c) {
                acc[c] = __builtin_amdgcn_mfma_f32_16x16x32_bf16(ah, bhv[c], acc[c], 0, 0, 0);
                acc[c] = __builtin_amdgcn_mfma_f32_16x16x32_bf16(al, bhv[c], acc[c], 0, 0, 0);
            }
        }
    }

    if (qs) {      // reduce across the 4 adjacent lanes sharing a row
#pragma unroll
        for (int off = 1; off < 4; off <<= 1) {
#pragma unroll
            for (int h = 0; h < 4; ++h) {
                qp[h] += __shfl_xor(qp[h], off, 64);
                kp[h] += __shfl_xor(kp[h], off, 64);
            }
        }
        if ((tid & 3) == 0) {
            int row = row0 + sr;
            if (row < M) {
                *(float4*)&qs[(size_t)row * HD] = make_float4(qp[0], qp[1], qp[2], qp[3]);
                *(float4*)&ks[(size_t)row * HD] = make_float4(kp[0], kp[1], kp[2], kp[3]);
            }
        }
    }

#pragma unroll
    for (int c = 0; c < 8; ++c) {
        float bv = bias ? bias[c * 16 + fr] : 0.f;
#pragma unroll
        for (int i = 0; i < 4; ++i) {
            int row = row0 + wave * 16 + fg * 4 + i;
            if (row < M) {
                float val = acc[c][i] + bv;
                if (Chf) Chf[(size_t)row * DD + c * 16 + fr] = __float2half(val);
                else     Cf [(size_t)row * DD + c * 16 + fr] = val;
            }
        }
    }
}

// ---------------------------------------------------------------------------
// CSR build: histogram + hierarchical 3-kernel scan + packed scatter.
// ---------------------------------------------------------------------------
__global__ __launch_bounds__(256) void csr_count(
    const int* __restrict__ dstv, int* __restrict__ deg, int E)
{
    int t = blockIdx.x * 256 + threadIdx.x;
    if (t < E) atomicAdd(&deg[dstv[t]], 1);
}

__global__ __launch_bounds__(SCAN_T) void scan_partial(
    const int* __restrict__ deg, int* __restrict__ blksum, int N)
{
    __shared__ int red[SCAN_T];
    int chunk = (N + SCAN_B - 1) / SCAN_B;
    int b0 = blockIdx.x * chunk;
    int e0 = b0 + chunk; if (e0 > N) e0 = N;
    int s = 0;
    for (int i = b0 + threadIdx.x; i < e0; i += SCAN_T) s += deg[i];
    red[threadIdx.x] = s;
    __syncthreads();
    for (int off = SCAN_T / 2; off > 0; off >>= 1) {
        if (threadIdx.x < off) red[threadIdx.x] += red[threadIdx.x + off];
        __syncthreads();
    }
    if (threadIdx.x == 0) blksum[blockIdx.x] = red[0];
}

__global__ __launch_bounds__(64) void scan_blk(
    const int* __restrict__ blksum, int* __restrict__ blkoff)
{
    if (threadIdx.x == 0) {
        int acc = 0;
        for (int i = 0; i < SCAN_B; ++i) { blkoff[i] = acc; acc += blksum[i]; }
        blkoff[SCAN_B] = acc;
    }
}

__global__ __launch_bounds__(SCAN_T) void scan_final(
    const int* __restrict__ deg, const int* __restrict__ blkoff,
    int* __restrict__ row_ptr, int N)
{
    __shared__ int tsum[SCAN_T];
    int tid = threadIdx.x;
    int chunk = (N + SCAN_B - 1) / SCAN_B;
    int b0 = blockIdx.x * chunk;
    int e0 = b0 + chunk; if (e0 > N) e0 = N;
    int tchunk = (chunk + SCAN_T - 1) / SCAN_T;
    int tb = b0 + tid * tchunk;
    int te = tb + tchunk; if (te > e0) te = e0;
    int s = 0;
    for (int i = tb; i < te; ++i) s += deg[i];
    tsum[tid] = s;
    __syncthreads();
    for (int off = 1; off < SCAN_T; off <<= 1) {
        int v = (tid >= off) ? tsum[tid - off] : 0;
        __syncthreads();
        tsum[tid] += v;
        __syncthreads();
    }
    int base = blkoff[blockIdx.x] + ((tid == 0) ? 0 : tsum[tid - 1]);
    for (int i = tb; i < te; ++i) { row_ptr[i] = base; base += deg[i]; }
    if (blockIdx.x == SCAN_B - 1 && tid == SCAN_T - 1) row_ptr[N] = blkoff[SCAN_B];
}

__global__ __launch_bounds__(256) void csr_scatter(
    const int* __restrict__ srcv, const int* __restrict__ dstv,
    const int* __restrict__ etype, const float* __restrict__ ew,
    const int* __restrict__ row_ptr, int* __restrict__ cursor,
    int4* __restrict__ c_pack, int E)
{
    int e = blockIdx.x * 256 + threadIdx.x;
    if (e >= E) return;
    int d = dstv[e];
    int p = row_ptr[d] + atomicAdd(&cursor[d], 1);
    c_pack[p] = make_int4(srcv[e], etype[e], __float_as_int(ew[e]), 0);
}

// ---------------------------------------------------------------------------
// Fused per-layer edge+softmax+aggregate+epilogue. One wave per dst node.
// Batch-8 edge loop (deep MLP); v gathered as fp16.
// ---------------------------------------------------------------------------
__global__ __launch_bounds__(256) void fused_conv(
    const int* __restrict__ row_ptr, const int4* __restrict__ c_pack,
    const float* __restrict__ qs, const float* __restrict__ ks,
    const float* __restrict__ esum, const float* __restrict__ gate,
    const __half* __restrict__ v, const float* __restrict__ bias,
    float* __restrict__ out, int N, int do_elu)
{
    int gw = (blockIdx.x * 256 + threadIdx.x) >> 6;   // global wave id = node
    int lane = threadIdx.x & 63;
    if (gw >= N) return;
    const int n = gw;
    const int beg = row_ptr[n], end = row_ptr[n + 1];
    const int c0 = lane * 2;
    const int h = lane >> 4;
    const float L2E = 1.4426950408889634f;
    const float scL = 0.17677669529663687f * 1.4426950408889634f;  // (1/sqrt32)*log2e
    const float qh = qs[(size_t)n * HD + h];
    const float ghL = gate[h] * L2E;

    float num0 = 0.f, num1 = 0.f, den = 0.f;

    int j = beg;
    for (; j + 8 <= end; j += 8) {
        int4 p[8];
#pragma unroll
        for (int u = 0; u < 8; ++u) p[u] = c_pack[j + u];
        float kh[8], eh[8];
        float2 vv[8];
#pragma unroll
        for (int u = 0; u < 8; ++u) kh[u] = ks[(size_t)p[u].x * HD + h];
#pragma unroll
        for (int u = 0; u < 8; ++u) eh[u] = esum[(size_t)p[u].y * HD + h];
#pragma unroll
        for (int u = 0; u < 8; ++u)
            vv[u] = __half22float2(*(const __half2*)&v[(size_t)p[u].x * DD + c0]);
#pragma unroll
        for (int u = 0; u < 8; ++u) {
            float a = (qh + kh[u] + eh[u]) * scL + ghL * __int_as_float(p[u].z);
            a = a > 0.f ? a : 0.2f * a;
            float e = exp2f(a);
            den += e;
            num0 = fmaf(e, vv[u].x, num0);
            num1 = fmaf(e, vv[u].y, num1);
        }
    }
    for (; j + 4 <= end; j += 4) {
        int4 p0 = c_pack[j];
        int4 p1 = c_pack[j + 1];
        int4 p2 = c_pack[j + 2];
        int4 p3 = c_pack[j + 3];
        float kh0 = ks[(size_t)p0.x * HD + h];
        float kh1 = ks[(size_t)p1.x * HD + h];
        float kh2 = ks[(size_t)p2.x * HD + h];
        float kh3 = ks[(size_t)p3.x * HD + h];
        float eh0 = esum[(size_t)p0.y * HD + h];
        float eh1 = esum[(size_t)p1.y * HD + h];
        float eh2 = esum[(size_t)p2.y * HD + h];
        float eh3 = esum[(size_t)p3.y * HD + h];
        float2 vv0 = __half22float2(*(const __half2*)&v[(size_t)p0.x * DD + c0]);
        float2 vv1 = __half22float2(*(const __half2*)&v[(size_t)p1.x * DD + c0]);
        float2 vv2 = __half22float2(*(const __half2*)&v[(size_t)p2.x * DD + c0]);
        float2 vv3 = __half22float2(*(const __half2*)&v[(size_t)p3.x * DD + c0]);
        float a0 = (qh + kh0 + eh0) * scL + ghL * __int_as_float(p0.z);
        float a1 = (qh + kh1 + eh1) * scL + ghL * __int_as_float(p1.z);
        float a2 = (qh + kh2 + eh2) * scL + ghL * __int_as_float(p2.z);
        float a3 = (qh + kh3 + eh3) * scL + ghL * __int_as_float(p3.z);
        a0 = a0 > 0.f ? a0 : 0.2f * a0;
        a1 = a1 > 0.f ? a1 : 0.2f * a1;
        a2 = a2 > 0.f ? a2 : 0.2f * a2;
        a3 = a3 > 0.f ? a3 : 0.2f * a3;
        float e0 = exp2f(a0), e1 = exp2f(a1);
        float e2 = exp2f(a2), e3 = exp2f(a3);
        den += (e0 + e1) + (e2 + e3);
        num0 = fmaf(e0, vv0.x, num0); num1 = fmaf(e0, vv0.y, num1);
        num0 = fmaf(e1, vv1.x, num0); num1 = fmaf(e1, vv1.y, num1);
        num0 = fmaf(e2, vv2.x, num0); num1 = fmaf(e2, vv2.y, num1);
        num0 = fmaf(e3, vv3.x, num0); num1 = fmaf(e3, vv3.y, num1);
    }
    for (; j < end; ++j) {
        int4 cur = c_pack[j];
        float kh = ks[(size_t)cur.x * HD + h];
        float eh = esum[(size_t)cur.y * HD + h];
        float2 vv = __half22float2(*(const __half2*)&v[(size_t)cur.x * DD + c0]);
        float a = (qh + kh + eh) * scL + ghL * __int_as_float(cur.z);
        a = a > 0.f ? a : 0.2f * a;
        float e = exp2f(a);
        den += e;
        num0 = fmaf(e, vv.x, num0);
        num1 = fmaf(e, vv.y, num1);
    }

    float inv = 1.f / (den + 1e-16f);
    float r0 = num0 * inv + bias[c0];
    float r1 = num1 * inv + bias[c0 + 1];
    if (do_elu) {
        r0 = r0 > 0.f ? r0 : expm1f(r0);
        r1 = r1 > 0.f ? r1 : expm1f(r1);
    }
    *(float2*)&out[(size_t)n * DD + c0] = make_float2(r0, r1);
}

// ---------------------------------------------------------------------------
extern "C" void kernel_launch(void* const* d_in, const int* in_sizes, int n_in,
                              void* d_out, int out_size, void* d_ws, size_t ws_size,
                              hipStream_t stream)
{
    const int*   entity = (const int*)d_in[0];
    const int*   eidx   = (const int*)d_in[1];
    const int*   etype  = (const int*)d_in[2];
    const float* ew     = (const float*)d_in[3];
    const float* ent    = (const float*)d_in[4];
    const float* pw     = (const float*)d_in[5];
    const float* pb     = (const float*)d_in[6];
    const float* rel    = (const float*)d_in[7];
    const float* Wq     = (const float*)d_in[8];
    const float* Wk     = (const float*)d_in[9];
    const float* Wv     = (const float*)d_in[10];
    const float* We     = (const float*)d_in[11];
    const float* gate   = (const float*)d_in[12];
    const float* cb     = (const float*)d_in[13];

    const int N = in_sizes[0];
    const int E = in_sizes[2];
    const int F = in_sizes[4] / N;     // 256
    const int R = in_sizes[7] / DD;    // 200

    const int* srcv = eidx;
    const int* dstv = eidx + E;

    float* ws = (float*)d_ws;
    size_t o = 0;
    float* xbuf    = ws + o; o += (size_t)N * DD;
    __half* vbuf   = (__half*)(ws + o); o += (size_t)N * DD / 2;   // fp16 v
    float* qs      = ws + o; o += (size_t)N * HD;
    float* ks      = ws + o; o += (size_t)N * HD;
    float* Wqh     = ws + o; o += 2 * DD * HD;
    float* Wkh     = ws + o; o += 2 * DD * HD;
    float* esum    = ws + o; o += (size_t)2 * R * HD;
    int*   deg     = (int*)(ws + o); o += N;
    int*   cursor  = (int*)(ws + o); o += N;
    int*   row_ptr = (int*)(ws + o); o += (size_t)N + 1;
    int*   blksum  = (int*)(ws + o); o += SCAN_B;
    int*   blkoff  = (int*)(ws + o); o += SCAN_B + 1;
    o = (o + 3) & ~(size_t)3;                       // 16B-align
    int4*  c_pack  = (int4*)(ws + o); o += (size_t)E * 4;
    unsigned short* btp = (unsigned short*)(ws + o); o += 128 * 256 / 2;
    unsigned short* btv = (unsigned short*)(ws + o); o += 2 * DD * DD / 2;

    prep_kernel<<<16, 256, 0, stream>>>(Wq, Wk, We, rel, Wqh, Wkh, esum, R);
    prep_bt<<<(128 * 256 + 2 * DD * DD + 255) / 256, 256, 0, stream>>>(
        pw, Wv, btp, btv);

    // CSR build (layer-independent, built once)
    hipMemsetAsync(deg, 0, (size_t)2 * N * sizeof(int), stream);  // deg + cursor
    csr_count<<<(E + 255) / 256, 256, 0, stream>>>(dstv, deg, E);
    scan_partial<<<SCAN_B, SCAN_T, 0, stream>>>(deg, blksum, N);
    scan_blk<<<1, 64, 0, stream>>>(blksum, blkoff);
    scan_final<<<SCAN_B, SCAN_T, 0, stream>>>(deg, blkoff, row_ptr, N);
    csr_scatter<<<(E + 255) / 256, 256, 0, stream>>>(
        srcv, dstv, etype, ew, row_ptr, cursor, c_pack, E);

    const int gblk = (N + 63) / 64;
    // x0 = ent_table[entity] @ proj_w + proj_b   (MFMA, K=256, fp32 out)
    gemm_mfma<<<gblk, 256, 0, stream>>>(
        ent, entity, btp, pb, nullptr, nullptr,
        xbuf, nullptr, nullptr, nullptr, N, F);

    const int fblk = (N + 3) / 4;     // one 64-lane wave per node
    for (int l = 0; l < 2; ++l) {
        gemm_mfma<<<gblk, 256, 0, stream>>>(
            xbuf, nullptr, btv + (size_t)l * DD * DD, nullptr,
            Wqh + l * DD * HD, Wkh + l * DD * HD,
            nullptr, vbuf, qs, ks, N, DD);
        fused_conv<<<fblk, 256, 0, stream>>>(
            row_ptr, c_pack, qs, ks, esum + (size_t)l * R * HD,
            gate + l * HD, vbuf, cb + l * DD,
            (l == 0) ? xbuf : (float*)d_out, N, (l == 0) ? 1 : 0);
    }
}

// Round 21
// 236.401 us; speedup vs baseline: 1.1467x; 1.1467x over previous
//
#include <hip/hip_runtime.h>
#include <hip/hip_fp16.h>

#define HD 4      // heads
#define DD 128    // model dim
#define CC 32     // channels per head
#define SCAN_B 64
#define SCAN_T 256

typedef float  f32x4   __attribute__((ext_vector_type(4)));
typedef short  short8v __attribute__((ext_vector_type(8)));

__device__ __forceinline__ unsigned short f2bf(float x) {
    unsigned u = __float_as_uint(x);
    return (unsigned short)((u + 0x7FFFu + ((u >> 16) & 1u)) >> 16);
}
__device__ __forceinline__ float bf2f(unsigned short h) {
    return __uint_as_float((unsigned)h << 16);
}

// ---------------------------------------------------------------------------
// Precompute per-head weight column-sums and per-relation esum table.
// Multi-block: each block recomputes the tiny WehS and handles a grid-strided
// slice of esum; block 0 writes Wqh/Wkh.
// ---------------------------------------------------------------------------
__global__ __launch_bounds__(256) void prep_kernel(
    const float* __restrict__ Wq, const float* __restrict__ Wk,
    const float* __restrict__ We, const float* __restrict__ rel,
    float* __restrict__ Wqh, float* __restrict__ Wkh,
    float* __restrict__ esum, int R)
{
    __shared__ float WehS[2][DD][HD];   // 4 KB
    int tid = threadIdx.x;
    for (int i = tid; i < 2 * DD * HD; i += 256) {
        int l = i / (DD * HD);
        int d = (i / HD) % DD;
        int h = i % HD;
        const float* bq = Wq + ((size_t)l * DD + d) * DD + h * CC;
        const float* bk = Wk + ((size_t)l * DD + d) * DD + h * CC;
        const float* be = We + ((size_t)l * DD + d) * DD + h * CC;
        float sq = 0.f, sk = 0.f, se = 0.f;
        for (int c = 0; c < CC; ++c) { sq += bq[c]; sk += bk[c]; se += be[c]; }
        if (blockIdx.x == 0) { Wqh[i] = sq; Wkh[i] = sk; }
        WehS[l][d][h] = se;
    }
    __syncthreads();
    for (int i = blockIdx.x * 256 + tid; i < 2 * R * HD; i += gridDim.x * 256) {
        int l = i / (R * HD);
        int r = (i / HD) % R;
        int h = i % HD;
        const float* rp = rel + (size_t)r * DD;
        float a = 0.f;
        for (int d = 0; d < DD; ++d) a += rp[d] * WehS[l][d][h];
        esum[i] = a;
    }
}

// ---------------------------------------------------------------------------
// Transposed bf16 (hi-only) weight tables.
// ---------------------------------------------------------------------------
__global__ __launch_bounds__(256) void prep_bt(
    const float* __restrict__ pw, const float* __restrict__ Wv,
    unsigned short* __restrict__ btp, unsigned short* __restrict__ btv)
{
    int t = blockIdx.x * 256 + threadIdx.x;
    if (t < 128 * 256) {
        int col = t >> 8, k = t & 255;
        btp[(size_t)col * 256 + k] = f2bf(pw[(size_t)k * DD + col]);
    } else if (t < 128 * 256 + 2 * DD * DD) {
        int u = t - 128 * 256;
        int l = u >> 14;
        int r = u & 16383;
        int col = r >> 7, k = r & 127;
        btv[((size_t)l * DD + col) * DD + k] = f2bf(Wv[((size_t)l * DD + k) * DD + col]);
    }
}

// ---------------------------------------------------------------------------
// Split-bf16 MFMA GEMM, BK=128 chunks, one staging phase per chunk.
// ROUND-19 STRUCTURE (B staged in LDS — direct-global B regressed in r20).
// Output: fp32 C (if Cf) or fp16 C (if Chf).
// ---------------------------------------------------------------------------
__global__ __launch_bounds__(256) void gemm_mfma(
    const float* __restrict__ A, const int* __restrict__ gather,
    const unsigned short* __restrict__ bth, const float* __restrict__ bias,
    const float* __restrict__ Wqh, const float* __restrict__ Wkh,
    float* __restrict__ Cf, __half* __restrict__ Chf,
    float* __restrict__ qs, float* __restrict__ ks,
    int M, int K)
{
    __shared__ unsigned short AhL[4][4][64][8];   // 16 KB
    __shared__ unsigned short AlL[4][4][64][8];   // 16 KB
    __shared__ unsigned short BhL[4][8][64][8];   // 32 KB
    __shared__ float wq[DD * HD], wk[DD * HD];    // 4 KB

    const int tid = threadIdx.x;
    const int wave = tid >> 6, lane = tid & 63;
    const int row0 = blockIdx.x * 64;

    if (qs) {
        for (int i = tid; i < DD * HD; i += 256) { wq[i] = Wqh[i]; wk[i] = Wkh[i]; }
    }

    const int sr = tid >> 2;       // 0..63
    const int sks = tid & 3;       // 0..3
    int arow = row0 + sr; if (arow >= M) arow = M - 1;
    const int ga = gather ? gather[arow] : arow;
    const float* Ap = A + (size_t)ga * K + sks * 32;

    const int bc = tid >> 1;       // 0..127
    const int bh2 = (tid & 1) * 64;
    const unsigned short* Bp = bth + (size_t)bc * K + bh2;
    const int bct = bc >> 4, bfr = bc & 15;

    const int fr = lane & 15, fg = lane >> 4;

    f32x4 acc[8] = {};
    float qp[4] = {}, kp[4] = {};

    const int nch = K >> 7;        // 128-wide chunks
    for (int ch = 0; ch < nch; ++ch) {
        float4 a[8];
#pragma unroll
        for (int i = 0; i < 8; ++i) a[i] = *(const float4*)(Ap + ch * 128 + i * 4);
        short8v b[8];
#pragma unroll
        for (int i = 0; i < 8; ++i) b[i] = *(const short8v*)(Bp + ch * 128 + i * 8);

        if (ch) __syncthreads();

        {
            const int rt = sr >> 4, frr = sr & 15;
#pragma unroll
            for (int g = 0; g < 4; ++g) {
                float vv[8] = {a[g*2].x, a[g*2].y, a[g*2].z, a[g*2].w,
                               a[g*2+1].x, a[g*2+1].y, a[g*2+1].z, a[g*2+1].w};
                short8v hv, lv;
#pragma unroll
                for (int j = 0; j < 8; ++j) {
                    unsigned short h = f2bf(vv[j]);
                    hv[j] = (short)h;
                    lv[j] = (short)f2bf(vv[j] - bf2f(h));
                }
                *(short8v*)&AhL[rt][sks][g * 16 + frr][0] = hv;
                *(short8v*)&AlL[rt][sks][g * 16 + frr][0] = lv;
            }
        }
        if (qs) {
#pragma unroll
            for (int i = 0; i < 8; ++i) {
                const float arr[4] = {a[i].x, a[i].y, a[i].z, a[i].w};
#pragma unroll
                for (int j = 0; j < 4; ++j) {
                    int d = ch * 128 + sks * 32 + i * 4 + j;
                    float4 qw = *(const float4*)&wq[d * HD];
                    float4 kw = *(const float4*)&wk[d * HD];
                    qp[0] += arr[j] * qw.x; qp[1] += arr[j] * qw.y;
                    qp[2] += arr[j] * qw.z; qp[3] += arr[j] * qw.w;
                    kp[0] += arr[j] * kw.x; kp[1] += arr[j] * kw.y;
                    kp[2] += arr[j] * kw.z; kp[3] += arr[j] * kw.w;
                }
            }
        }
#pragma unroll
        for (int g = 0; g < 8; ++g) {
            int kk = bh2 + g * 8;
            int ksb = kk >> 5, fgb = (kk & 31) >> 3;
            *(short8v*)&BhL[ksb][bct][fgb * 16 + bfr][0] = b[g];
        }
        __syncthreads();

#pragma unroll
        for (int ksc = 0; ksc < 4; ++ksc) {
            short8v ah = *(const short8v*)&AhL[wave][ksc][lane][0];
            short8v al = *(const short8v*)&AlL[wave][ksc][lane][0];
#pragma unroll
            for (int c = 0; c < 8; ++c) {
                short8v bh = *(const short8v*)&BhL[ksc][c][lane][0];
                acc[c] = __builtin_amdgcn_mfma_f32_16x16x32_bf16(ah, bh, acc[c], 0, 0, 0);
                acc[c] = __builtin_amdgcn_mfma_f32_16x16x32_bf16(al, bh, acc[c], 0, 0, 0);
            }
        }
    }

    if (qs) {
#pragma unroll
        for (int off = 1; off < 4; off <<= 1) {
#pragma unroll
            for (int h = 0; h < 4; ++h) {
                qp[h] += __shfl_xor(qp[h], off, 64);
                kp[h] += __shfl_xor(kp[h], off, 64);
            }
        }
        if ((tid & 3) == 0) {
            int row = row0 + sr;
            if (row < M) {
                *(float4*)&qs[(size_t)row * HD] = make_float4(qp[0], qp[1], qp[2], qp[3]);
                *(float4*)&ks[(size_t)row * HD] = make_float4(kp[0], kp[1], kp[2], kp[3]);
            }
        }
    }

#pragma unroll
    for (int c = 0; c < 8; ++c) {
        float bv = bias ? bias[c * 16 + fr] : 0.f;
#pragma unroll
        for (int i = 0; i < 4; ++i) {
            int row = row0 + wave * 16 + fg * 4 + i;
            if (row < M) {
                float val = acc[c][i] + bv;
                if (Chf) Chf[(size_t)row * DD + c * 16 + fr] = __float2half(val);
                else     Cf [(size_t)row * DD + c * 16 + fr] = val;
            }
        }
    }
}

// ---------------------------------------------------------------------------
// CSR build: histogram + hierarchical 3-kernel scan + packed scatter.
// ---------------------------------------------------------------------------
__global__ __launch_bounds__(256) void csr_count(
    const int* __restrict__ dstv, int* __restrict__ deg, int E)
{
    int t = blockIdx.x * 256 + threadIdx.x;
    if (t < E) atomicAdd(&deg[dstv[t]], 1);
}

__global__ __launch_bounds__(SCAN_T) void scan_partial(
    const int* __restrict__ deg, int* __restrict__ blksum, int N)
{
    __shared__ int red[SCAN_T];
    int chunk = (N + SCAN_B - 1) / SCAN_B;
    int b0 = blockIdx.x * chunk;
    int e0 = b0 + chunk; if (e0 > N) e0 = N;
    int s = 0;
    for (int i = b0 + threadIdx.x; i < e0; i += SCAN_T) s += deg[i];
    red[threadIdx.x] = s;
    __syncthreads();
    for (int off = SCAN_T / 2; off > 0; off >>= 1) {
        if (threadIdx.x < off) red[threadIdx.x] += red[threadIdx.x + off];
        __syncthreads();
    }
    if (threadIdx.x == 0) blksum[blockIdx.x] = red[0];
}

__global__ __launch_bounds__(64) void scan_blk(
    const int* __restrict__ blksum, int* __restrict__ blkoff)
{
    if (threadIdx.x == 0) {
        int acc = 0;
        for (int i = 0; i < SCAN_B; ++i) { blkoff[i] = acc; acc += blksum[i]; }
        blkoff[SCAN_B] = acc;
    }
}

__global__ __launch_bounds__(SCAN_T) void scan_final(
    const int* __restrict__ deg, const int* __restrict__ blkoff,
    int* __restrict__ row_ptr, int N)
{
    __shared__ int tsum[SCAN_T];
    int tid = threadIdx.x;
    int chunk = (N + SCAN_B - 1) / SCAN_B;
    int b0 = blockIdx.x * chunk;
    int e0 = b0 + chunk; if (e0 > N) e0 = N;
    int tchunk = (chunk + SCAN_T - 1) / SCAN_T;
    int tb = b0 + tid * tchunk;
    int te = tb + tchunk; if (te > e0) te = e0;
    int s = 0;
    for (int i = tb; i < te; ++i) s += deg[i];
    tsum[tid] = s;
    __syncthreads();
    for (int off = 1; off < SCAN_T; off <<= 1) {
        int v = (tid >= off) ? tsum[tid - off] : 0;
        __syncthreads();
        tsum[tid] += v;
        __syncthreads();
    }
    int base = blkoff[blockIdx.x] + ((tid == 0) ? 0 : tsum[tid - 1]);
    for (int i = tb; i < te; ++i) { row_ptr[i] = base; base += deg[i]; }
    if (blockIdx.x == SCAN_B - 1 && tid == SCAN_T - 1) row_ptr[N] = blkoff[SCAN_B];
}

__global__ __launch_bounds__(256) void csr_scatter(
    const int* __restrict__ srcv, const int* __restrict__ dstv,
    const int* __restrict__ etype, const float* __restrict__ ew,
    const int* __restrict__ row_ptr, int* __restrict__ cursor,
    int4* __restrict__ c_pack, int E)
{
    int e = blockIdx.x * 256 + threadIdx.x;
    if (e >= E) return;
    int d = dstv[e];
    int p = row_ptr[d] + atomicAdd(&cursor[d], 1);
    c_pack[p] = make_int4(srcv[e], etype[e], __float_as_int(ew[e]), 0);
}

// ---------------------------------------------------------------------------
// Fused per-layer edge+softmax+aggregate+epilogue. One wave per dst node.
// Batch-8 edge loop; v gathered as fp16.
// ---------------------------------------------------------------------------
__global__ __launch_bounds__(256) void fused_conv(
    const int* __restrict__ row_ptr, const int4* __restrict__ c_pack,
    const float* __restrict__ qs, const float* __restrict__ ks,
    const float* __restrict__ esum, const float* __restrict__ gate,
    const __half* __restrict__ v, const float* __restrict__ bias,
    float* __restrict__ out, int N, int do_elu)
{
    int gw = (blockIdx.x * 256 + threadIdx.x) >> 6;   // global wave id = node
    int lane = threadIdx.x & 63;
    if (gw >= N) return;
    const int n = gw;
    const int beg = row_ptr[n], end = row_ptr[n + 1];
    const int c0 = lane * 2;
    const int h = lane >> 4;
    const float L2E = 1.4426950408889634f;
    const float scL = 0.17677669529663687f * 1.4426950408889634f;  // (1/sqrt32)*log2e
    const float qh = qs[(size_t)n * HD + h];
    const float ghL = gate[h] * L2E;

    float num0 = 0.f, num1 = 0.f, den = 0.f;

    int j = beg;
    for (; j + 8 <= end; j += 8) {
        int4 p[8];
#pragma unroll
        for (int u = 0; u < 8; ++u) p[u] = c_pack[j + u];
        float kh[8], eh[8];
        float2 vv[8];
#pragma unroll
        for (int u = 0; u < 8; ++u) kh[u] = ks[(size_t)p[u].x * HD + h];
#pragma unroll
        for (int u = 0; u < 8; ++u) eh[u] = esum[(size_t)p[u].y * HD + h];
#pragma unroll
        for (int u = 0; u < 8; ++u)
            vv[u] = __half22float2(*(const __half2*)&v[(size_t)p[u].x * DD + c0]);
#pragma unroll
        for (int u = 0; u < 8; ++u) {
            float a = (qh + kh[u] + eh[u]) * scL + ghL * __int_as_float(p[u].z);
            a = a > 0.f ? a : 0.2f * a;
            float e = exp2f(a);
            den += e;
            num0 = fmaf(e, vv[u].x, num0);
            num1 = fmaf(e, vv[u].y, num1);
        }
    }
    for (; j + 4 <= end; j += 4) {
        int4 p0 = c_pack[j];
        int4 p1 = c_pack[j + 1];
        int4 p2 = c_pack[j + 2];
        int4 p3 = c_pack[j + 3];
        float kh0 = ks[(size_t)p0.x * HD + h];
        float kh1 = ks[(size_t)p1.x * HD + h];
        float kh2 = ks[(size_t)p2.x * HD + h];
        float kh3 = ks[(size_t)p3.x * HD + h];
        float eh0 = esum[(size_t)p0.y * HD + h];
        float eh1 = esum[(size_t)p1.y * HD + h];
        float eh2 = esum[(size_t)p2.y * HD + h];
        float eh3 = esum[(size_t)p3.y * HD + h];
        float2 vv0 = __half22float2(*(const __half2*)&v[(size_t)p0.x * DD + c0]);
        float2 vv1 = __half22float2(*(const __half2*)&v[(size_t)p1.x * DD + c0]);
        float2 vv2 = __half22float2(*(const __half2*)&v[(size_t)p2.x * DD + c0]);
        float2 vv3 = __half22float2(*(const __half2*)&v[(size_t)p3.x * DD + c0]);
        float a0 = (qh + kh0 + eh0) * scL + ghL * __int_as_float(p0.z);
        float a1 = (qh + kh1 + eh1) * scL + ghL * __int_as_float(p1.z);
        float a2 = (qh + kh2 + eh2) * scL + ghL * __int_as_float(p2.z);
        float a3 = (qh + kh3 + eh3) * scL + ghL * __int_as_float(p3.z);
        a0 = a0 > 0.f ? a0 : 0.2f * a0;
        a1 = a1 > 0.f ? a1 : 0.2f * a1;
        a2 = a2 > 0.f ? a2 : 0.2f * a2;
        a3 = a3 > 0.f ? a3 : 0.2f * a3;
        float e0 = exp2f(a0), e1 = exp2f(a1);
        float e2 = exp2f(a2), e3 = exp2f(a3);
        den += (e0 + e1) + (e2 + e3);
        num0 = fmaf(e0, vv0.x, num0); num1 = fmaf(e0, vv0.y, num1);
        num0 = fmaf(e1, vv1.x, num0); num1 = fmaf(e1, vv1.y, num1);
        num0 = fmaf(e2, vv2.x, num0); num1 = fmaf(e2, vv2.y, num1);
        num0 = fmaf(e3, vv3.x, num0); num1 = fmaf(e3, vv3.y, num1);
    }
    for (; j < end; ++j) {
        int4 cur = c_pack[j];
        float kh = ks[(size_t)cur.x * HD + h];
        float eh = esum[(size_t)cur.y * HD + h];
        float2 vv = __half22float2(*(const __half2*)&v[(size_t)cur.x * DD + c0]);
        float a = (qh + kh + eh) * scL + ghL * __int_as_float(cur.z);
        a = a > 0.f ? a : 0.2f * a;
        float e = exp2f(a);
        den += e;
        num0 = fmaf(e, vv.x, num0);
        num1 = fmaf(e, vv.y, num1);
    }

    float inv = 1.f / (den + 1e-16f);
    float r0 = num0 * inv + bias[c0];
    float r1 = num1 * inv + bias[c0 + 1];
    if (do_elu) {
        r0 = r0 > 0.f ? r0 : expm1f(r0);
        r1 = r1 > 0.f ? r1 : expm1f(r1);
    }
    *(float2*)&out[(size_t)n * DD + c0] = make_float2(r0, r1);
}

// ---------------------------------------------------------------------------
extern "C" void kernel_launch(void* const* d_in, const int* in_sizes, int n_in,
                              void* d_out, int out_size, void* d_ws, size_t ws_size,
                              hipStream_t stream)
{
    const int*   entity = (const int*)d_in[0];
    const int*   eidx   = (const int*)d_in[1];
    const int*   etype  = (const int*)d_in[2];
    const float* ew     = (const float*)d_in[3];
    const float* ent    = (const float*)d_in[4];
    const float* pw     = (const float*)d_in[5];
    const float* pb     = (const float*)d_in[6];
    const float* rel    = (const float*)d_in[7];
    const float* Wq     = (const float*)d_in[8];
    const float* Wk     = (const float*)d_in[9];
    const float* Wv     = (const float*)d_in[10];
    const float* We     = (const float*)d_in[11];
    const float* gate   = (const float*)d_in[12];
    const float* cb     = (const float*)d_in[13];

    const int N = in_sizes[0];
    const int E = in_sizes[2];
    const int F = in_sizes[4] / N;     // 256
    const int R = in_sizes[7] / DD;    // 200

    const int* srcv = eidx;
    const int* dstv = eidx + E;

    float* ws = (float*)d_ws;
    size_t o = 0;
    float* xbuf    = ws + o; o += (size_t)N * DD;
    __half* vbuf   = (__half*)(ws + o); o += (size_t)N * DD / 2;   // fp16 v
    float* qs      = ws + o; o += (size_t)N * HD;
    float* ks      = ws + o; o += (size_t)N * HD;
    float* Wqh     = ws + o; o += 2 * DD * HD;
    float* Wkh     = ws + o; o += 2 * DD * HD;
    float* esum    = ws + o; o += (size_t)2 * R * HD;
    int*   deg     = (int*)(ws + o); o += N;
    int*   cursor  = (int*)(ws + o); o += N;
    int*   row_ptr = (int*)(ws + o); o += (size_t)N + 1;
    int*   blksum  = (int*)(ws + o); o += SCAN_B;
    int*   blkoff  = (int*)(ws + o); o += SCAN_B + 1;
    o = (o + 3) & ~(size_t)3;                       // 16B-align
    int4*  c_pack  = (int4*)(ws + o); o += (size_t)E * 4;
    unsigned short* btp = (unsigned short*)(ws + o); o += 128 * 256 / 2;
    unsigned short* btv = (unsigned short*)(ws + o); o += 2 * DD * DD / 2;

    prep_kernel<<<16, 256, 0, stream>>>(Wq, Wk, We, rel, Wqh, Wkh, esum, R);
    prep_bt<<<(128 * 256 + 2 * DD * DD + 255) / 256, 256, 0, stream>>>(
        pw, Wv, btp, btv);

    // CSR build (layer-independent, built once)
    hipMemsetAsync(deg, 0, (size_t)2 * N * sizeof(int), stream);  // deg + cursor
    csr_count<<<(E + 255) / 256, 256, 0, stream>>>(dstv, deg, E);
    scan_partial<<<SCAN_B, SCAN_T, 0, stream>>>(deg, blksum, N);
    scan_blk<<<1, 64, 0, stream>>>(blksum, blkoff);
    scan_final<<<SCAN_B, SCAN_T, 0, stream>>>(deg, blkoff, row_ptr, N);
    csr_scatter<<<(E + 255) / 256, 256, 0, stream>>>(
        srcv, dstv, etype, ew, row_ptr, cursor, c_pack, E);

    const int gblk = (N + 63) / 64;
    // x0 = ent_table[entity] @ proj_w + proj_b   (MFMA, K=256, fp32 out)
    gemm_mfma<<<gblk, 256, 0, stream>>>(
        ent, entity, btp, pb, nullptr, nullptr,
        xbuf, nullptr, nullptr, nullptr, N, F);

    const int fblk = (N + 3) / 4;     // one 64-lane wave per node
    for (int l = 0; l < 2; ++l) {
        gemm_mfma<<<gblk, 256, 0, stream>>>(
            xbuf, nullptr, btv + (size_t)l * DD * DD, nullptr,
            Wqh + l * DD * HD, Wkh + l * DD * HD,
            nullptr, vbuf, qs, ks, N, DD);
        fused_conv<<<fblk, 256, 0, stream>>>(
            row_ptr, c_pack, qs, ks, esum + (size_t)l * R * HD,
            gate + l * HD, vbuf, cb + l * DD,
            (l == 0) ? xbuf : (float*)d_out, N, (l == 0) ? 1 : 0);
    }
}

// Round 24
// 226.805 us; speedup vs baseline: 1.1952x; 1.0423x over previous
//
#include <hip/hip_runtime.h>
#include <hip/hip_fp16.h>

#define HD 4      // heads
#define DD 128    // model dim
#define CC 32     // channels per head
#define SCAN_B 64
#define SCAN_T 256

typedef float  f32x4   __attribute__((ext_vector_type(4)));
typedef short  short8v __attribute__((ext_vector_type(8)));

__device__ __forceinline__ unsigned short f2bf(float x) {
    unsigned u = __float_as_uint(x);
    return (unsigned short)((u + 0x7FFFu + ((u >> 16) & 1u)) >> 16);
}
__device__ __forceinline__ float bf2f(unsigned short h) {
    return __uint_as_float((unsigned)h << 16);
}

// ---------------------------------------------------------------------------
// Precompute per-head weight column-sums and per-relation esum table.
// ---------------------------------------------------------------------------
__global__ __launch_bounds__(256) void prep_kernel(
    const float* __restrict__ Wq, const float* __restrict__ Wk,
    const float* __restrict__ We, const float* __restrict__ rel,
    float* __restrict__ Wqh, float* __restrict__ Wkh,
    float* __restrict__ esum, int R)
{
    __shared__ float WehS[2][DD][HD];   // 4 KB
    int tid = threadIdx.x;
    for (int i = tid; i < 2 * DD * HD; i += 256) {
        int l = i / (DD * HD);
        int d = (i / HD) % DD;
        int h = i % HD;
        const float* bq = Wq + ((size_t)l * DD + d) * DD + h * CC;
        const float* bk = Wk + ((size_t)l * DD + d) * DD + h * CC;
        const float* be = We + ((size_t)l * DD + d) * DD + h * CC;
        float sq = 0.f, sk = 0.f, se = 0.f;
        for (int c = 0; c < CC; ++c) { sq += bq[c]; sk += bk[c]; se += be[c]; }
        if (blockIdx.x == 0) { Wqh[i] = sq; Wkh[i] = sk; }
        WehS[l][d][h] = se;
    }
    __syncthreads();
    for (int i = blockIdx.x * 256 + tid; i < 2 * R * HD; i += gridDim.x * 256) {
        int l = i / (R * HD);
        int r = (i / HD) % R;
        int h = i % HD;
        const float* rp = rel + (size_t)r * DD;
        float a = 0.f;
        for (int d = 0; d < DD; ++d) a += rp[d] * WehS[l][d][h];
        esum[i] = a;
    }
}

// ---------------------------------------------------------------------------
// Transposed bf16 (hi-only) weight tables.
// ---------------------------------------------------------------------------
__global__ __launch_bounds__(256) void prep_bt(
    const float* __restrict__ pw, const float* __restrict__ Wv,
    unsigned short* __restrict__ btp, unsigned short* __restrict__ btv)
{
    int t = blockIdx.x * 256 + threadIdx.x;
    if (t < 128 * 256) {
        int col = t >> 8, k = t & 255;
        btp[(size_t)col * 256 + k] = f2bf(pw[(size_t)k * DD + col]);
    } else if (t < 128 * 256 + 2 * DD * DD) {
        int u = t - 128 * 256;
        int l = u >> 14;
        int r = u & 16383;
        int col = r >> 7, k = r & 127;
        btv[((size_t)l * DD + col) * DD + k] = f2bf(Wv[((size_t)l * DD + k) * DD + col]);
    }
}

// ---------------------------------------------------------------------------
// Split-bf16 MFMA GEMM (round-19 structure: B staged in LDS).
// ---------------------------------------------------------------------------
__global__ __launch_bounds__(256) void gemm_mfma(
    const float* __restrict__ A, const int* __restrict__ gather,
    const unsigned short* __restrict__ bth, const float* __restrict__ bias,
    const float* __restrict__ Wqh, const float* __restrict__ Wkh,
    float* __restrict__ Cf, __half* __restrict__ Chf,
    float* __restrict__ qs, float* __restrict__ ks,
    int M, int K)
{
    __shared__ unsigned short AhL[4][4][64][8];   // 16 KB
    __shared__ unsigned short AlL[4][4][64][8];   // 16 KB
    __shared__ unsigned short BhL[4][8][64][8];   // 32 KB
    __shared__ float wq[DD * HD], wk[DD * HD];    // 4 KB

    const int tid = threadIdx.x;
    const int wave = tid >> 6, lane = tid & 63;
    const int row0 = blockIdx.x * 64;

    if (qs) {
        for (int i = tid; i < DD * HD; i += 256) { wq[i] = Wqh[i]; wk[i] = Wkh[i]; }
    }

    const int sr = tid >> 2;       // 0..63
    const int sks = tid & 3;       // 0..3
    int arow = row0 + sr; if (arow >= M) arow = M - 1;
    const int ga = gather ? gather[arow] : arow;
    const float* Ap = A + (size_t)ga * K + sks * 32;

    const int bc = tid >> 1;       // 0..127
    const int bh2 = (tid & 1) * 64;
    const unsigned short* Bp = bth + (size_t)bc * K + bh2;
    const int bct = bc >> 4, bfr = bc & 15;

    const int fr = lane & 15, fg = lane >> 4;

    f32x4 acc[8] = {};
    float qp[4] = {}, kp[4] = {};

    const int nch = K >> 7;        // 128-wide chunks
    for (int ch = 0; ch < nch; ++ch) {
        float4 a[8];
#pragma unroll
        for (int i = 0; i < 8; ++i) a[i] = *(const float4*)(Ap + ch * 128 + i * 4);
        short8v b[8];
#pragma unroll
        for (int i = 0; i < 8; ++i) b[i] = *(const short8v*)(Bp + ch * 128 + i * 8);

        if (ch) __syncthreads();

        {
            const int rt = sr >> 4, frr = sr & 15;
#pragma unroll
            for (int g = 0; g < 4; ++g) {
                float vv[8] = {a[g*2].x, a[g*2].y, a[g*2].z, a[g*2].w,
                               a[g*2+1].x, a[g*2+1].y, a[g*2+1].z, a[g*2+1].w};
                short8v hv, lv;
#pragma unroll
                for (int j = 0; j < 8; ++j) {
                    unsigned short h = f2bf(vv[j]);
                    hv[j] = (short)h;
                    lv[j] = (short)f2bf(vv[j] - bf2f(h));
                }
                *(short8v*)&AhL[rt][sks][g * 16 + frr][0] = hv;
                *(short8v*)&AlL[rt][sks][g * 16 + frr][0] = lv;
            }
        }
        if (qs) {
#pragma unroll
            for (int i = 0; i < 8; ++i) {
                const float arr[4] = {a[i].x, a[i].y, a[i].z, a[i].w};
#pragma unroll
                for (int j = 0; j < 4; ++j) {
                    int d = ch * 128 + sks * 32 + i * 4 + j;
                    float4 qw = *(const float4*)&wq[d * HD];
                    float4 kw = *(const float4*)&wk[d * HD];
                    qp[0] += arr[j] * qw.x; qp[1] += arr[j] * qw.y;
                    qp[2] += arr[j] * qw.z; qp[3] += arr[j] * qw.w;
                    kp[0] += arr[j] * kw.x; kp[1] += arr[j] * kw.y;
                    kp[2] += arr[j] * kw.z; kp[3] += arr[j] * kw.w;
                }
            }
        }
#pragma unroll
        for (int g = 0; g < 8; ++g) {
            int kk = bh2 + g * 8;
            int ksb = kk >> 5, fgb = (kk & 31) >> 3;
            *(short8v*)&BhL[ksb][bct][fgb * 16 + bfr][0] = b[g];
        }
        __syncthreads();

#pragma unroll
        for (int ksc = 0; ksc < 4; ++ksc) {
            short8v ah = *(const short8v*)&AhL[wave][ksc][lane][0];
            short8v al = *(const short8v*)&AlL[wave][ksc][lane][0];
#pragma unroll
            for (int c = 0; c < 8; ++c) {
                short8v bh = *(const short8v*)&BhL[ksc][c][lane][0];
                acc[c] = __builtin_amdgcn_mfma_f32_16x16x32_bf16(ah, bh, acc[c], 0, 0, 0);
                acc[c] = __builtin_amdgcn_mfma_f32_16x16x32_bf16(al, bh, acc[c], 0, 0, 0);
            }
        }
    }

    if (qs) {
#pragma unroll
        for (int off = 1; off < 4; off <<= 1) {
#pragma unroll
            for (int h = 0; h < 4; ++h) {
                qp[h] += __shfl_xor(qp[h], off, 64);
                kp[h] += __shfl_xor(kp[h], off, 64);
            }
        }
        if ((tid & 3) == 0) {
            int row = row0 + sr;
            if (row < M) {
                *(float4*)&qs[(size_t)row * HD] = make_float4(qp[0], qp[1], qp[2], qp[3]);
                *(float4*)&ks[(size_t)row * HD] = make_float4(kp[0], kp[1], kp[2], kp[3]);
            }
        }
    }

#pragma unroll
    for (int c = 0; c < 8; ++c) {
        float bv = bias ? bias[c * 16 + fr] : 0.f;
#pragma unroll
        for (int i = 0; i < 4; ++i) {
            int row = row0 + wave * 16 + fg * 4 + i;
            if (row < M) {
                float val = acc[c][i] + bv;
                if (Chf) Chf[(size_t)row * DD + c * 16 + fr] = __float2half(val);
                else     Cf [(size_t)row * DD + c * 16 + fr] = val;
            }
        }
    }
}

// ---------------------------------------------------------------------------
// CSR build: histogram + hierarchical 3-kernel scan + packed scatter.
// ---------------------------------------------------------------------------
__global__ __launch_bounds__(256) void csr_count(
    const int* __restrict__ dstv, int* __restrict__ deg, int E)
{
    int t = blockIdx.x * 256 + threadIdx.x;
    if (t < E) atomicAdd(&deg[dstv[t]], 1);
}

__global__ __launch_bounds__(SCAN_T) void scan_partial(
    const int* __restrict__ deg, int* __restrict__ blksum, int N)
{
    __shared__ int red[SCAN_T];
    int chunk = (N + SCAN_B - 1) / SCAN_B;
    int b0 = blockIdx.x * chunk;
    int e0 = b0 + chunk; if (e0 > N) e0 = N;
    int s = 0;
    for (int i = b0 + threadIdx.x; i < e0; i += SCAN_T) s += deg[i];
    red[threadIdx.x] = s;
    __syncthreads();
    for (int off = SCAN_T / 2; off > 0; off >>= 1) {
        if (threadIdx.x < off) red[threadIdx.x] += red[threadIdx.x + off];
        __syncthreads();
    }
    if (threadIdx.x == 0) blksum[blockIdx.x] = red[0];
}

__global__ __launch_bounds__(64) void scan_blk(
    const int* __restrict__ blksum, int* __restrict__ blkoff)
{
    if (threadIdx.x == 0) {
        int acc = 0;
        for (int i = 0; i < SCAN_B; ++i) { blkoff[i] = acc; acc += blksum[i]; }
        blkoff[SCAN_B] = acc;
    }
}

__global__ __launch_bounds__(SCAN_T) void scan_final(
    const int* __restrict__ deg, const int* __restrict__ blkoff,
    int* __restrict__ row_ptr, int N)
{
    __shared__ int tsum[SCAN_T];
    int tid = threadIdx.x;
    int chunk = (N + SCAN_B - 1) / SCAN_B;
    int b0 = blockIdx.x * chunk;
    int e0 = b0 + chunk; if (e0 > N) e0 = N;
    int tchunk = (chunk + SCAN_T - 1) / SCAN_T;
    int tb = b0 + tid * tchunk;
    int te = tb + tchunk; if (te > e0) te = e0;
    int s = 0;
    for (int i = tb; i < te; ++i) s += deg[i];
    tsum[tid] = s;
    __syncthreads();
    for (int off = 1; off < SCAN_T; off <<= 1) {
        int v = (tid >= off) ? tsum[tid - off] : 0;
        __syncthreads();
        tsum[tid] += v;
        __syncthreads();
    }
    int base = blkoff[blockIdx.x] + ((tid == 0) ? 0 : tsum[tid - 1]);
    for (int i = tb; i < te; ++i) { row_ptr[i] = base; base += deg[i]; }
    if (blockIdx.x == SCAN_B - 1 && tid == SCAN_T - 1) row_ptr[N] = blkoff[SCAN_B];
}

__global__ __launch_bounds__(256) void csr_scatter(
    const int* __restrict__ srcv, const int* __restrict__ dstv,
    const int* __restrict__ etype, const float* __restrict__ ew,
    const int* __restrict__ row_ptr, int* __restrict__ cursor,
    int4* __restrict__ c_pack, int* __restrict__ c_src, int E)
{
    int e = blockIdx.x * 256 + threadIdx.x;
    if (e >= E) return;
    int d = dstv[e];
    int p = row_ptr[d] + atomicAdd(&cursor[d], 1);
    c_pack[p] = make_int4(srcv[e], etype[e], __float_as_int(ew[e]), 0);
    c_src[p] = srcv[e];
}

// ---------------------------------------------------------------------------
// Per-layer edge precompute: bedge[e][h] = (ks[src][h]+esum[et][h])*scL
//                                          + gate[h]*log2e*w.
// Edge-parallel, ks (800 KB) L2-resident, coalesced 16B writes.
// ---------------------------------------------------------------------------
__global__ __launch_bounds__(256) void edge_prep(
    const int4* __restrict__ c_pack, const float* __restrict__ ks,
    const float* __restrict__ esum, const float* __restrict__ gate,
    float4* __restrict__ bedge, int E)
{
    int t = blockIdx.x * 256 + threadIdx.x;
    if (t >= E) return;
    const float L2E = 1.4426950408889634f;
    const float scL = 0.17677669529663687f * 1.4426950408889634f;
    int4 p = c_pack[t];
    float w = __int_as_float(p.z);
    float4 kv = *(const float4*)&ks[(size_t)p.x * HD];
    float4 ev = *(const float4*)&esum[(size_t)p.y * HD];
    float4 g  = *(const float4*)gate;
    float4 b;
    b.x = (kv.x + ev.x) * scL + g.x * L2E * w;
    b.y = (kv.y + ev.y) * scL + g.y * L2E * w;
    b.z = (kv.z + ev.z) * scL + g.z * L2E * w;
    b.w = (kv.w + ev.w) * scL + g.w * L2E * w;
    bedge[t] = b;
}

// ---------------------------------------------------------------------------
// Fused per-layer softmax+aggregate+epilogue. One wave per dst node.
// Per edge: uniform c_src + uniform bedge (sequential stream) + one random
// fp16 v-gather + 7 VALU ops. Batch-8 with 4/1 tails.
// ---------------------------------------------------------------------------
__global__ __launch_bounds__(256) void fused_conv(
    const int* __restrict__ row_ptr, const int* __restrict__ c_src,
    const float* __restrict__ bedge, const float* __restrict__ qs,
    const __half* __restrict__ v, const float* __restrict__ bias,
    float* __restrict__ out, int N, int do_elu)
{
    int gw = (blockIdx.x * 256 + threadIdx.x) >> 6;   // global wave id = node
    int lane = threadIdx.x & 63;
    if (gw >= N) return;
    const int n = gw;
    const int beg = row_ptr[n], end = row_ptr[n + 1];
    const int c0 = lane * 2;
    const int h = lane >> 4;
    const float scL = 0.17677669529663687f * 1.4426950408889634f;
    const float qhs = qs[(size_t)n * HD + h] * scL;

    float num0 = 0.f, num1 = 0.f, den = 0.f;

    int j = beg;
    for (; j + 8 <= end; j += 8) {
        int s[8]; float bh[8]; float2 vv[8];
#pragma unroll
        for (int u = 0; u < 8; ++u) s[u] = c_src[j + u];
#pragma unroll
        for (int u = 0; u < 8; ++u) bh[u] = bedge[(size_t)(j + u) * HD + h];
#pragma unroll
        for (int u = 0; u < 8; ++u)
            vv[u] = __half22float2(*(const __half2*)&v[(size_t)s[u] * DD + c0]);
#pragma unroll
        for (int u = 0; u < 8; ++u) {
            float a = qhs + bh[u];
            a = a > 0.f ? a : 0.2f * a;
            float e = exp2f(a);
            den += e;
            num0 = fmaf(e, vv[u].x, num0);
            num1 = fmaf(e, vv[u].y, num1);
        }
    }
    for (; j + 4 <= end; j += 4) {
        int s0 = c_src[j], s1 = c_src[j + 1], s2 = c_src[j + 2], s3 = c_src[j + 3];
        float b0 = bedge[(size_t)j * HD + h];
        float b1 = bedge[(size_t)(j + 1) * HD + h];
        float b2 = bedge[(size_t)(j + 2) * HD + h];
        float b3 = bedge[(size_t)(j + 3) * HD + h];
        float2 vv0 = __half22float2(*(const __half2*)&v[(size_t)s0 * DD + c0]);
        float2 vv1 = __half22float2(*(const __half2*)&v[(size_t)s1 * DD + c0]);
        float2 vv2 = __half22float2(*(const __half2*)&v[(size_t)s2 * DD + c0]);
        float2 vv3 = __half22float2(*(const __half2*)&v[(size_t)s3 * DD + c0]);
        float a0 = qhs + b0, a1 = qhs + b1, a2 = qhs + b2, a3 = qhs + b3;
        a0 = a0 > 0.f ? a0 : 0.2f * a0;
        a1 = a1 > 0.f ? a1 : 0.2f * a1;
        a2 = a2 > 0.f ? a2 : 0.2f * a2;
        a3 = a3 > 0.f ? a3 : 0.2f * a3;
        float e0 = exp2f(a0), e1 = exp2f(a1);
        float e2 = exp2f(a2), e3 = exp2f(a3);
        den += (e0 + e1) + (e2 + e3);
        num0 = fmaf(e0, vv0.x, num0); num1 = fmaf(e0, vv0.y, num1);
        num0 = fmaf(e1, vv1.x, num0); num1 = fmaf(e1, vv1.y, num1);
        num0 = fmaf(e2, vv2.x, num0); num1 = fmaf(e2, vv2.y, num1);
        num0 = fmaf(e3, vv3.x, num0); num1 = fmaf(e3, vv3.y, num1);
    }
    for (; j < end; ++j) {
        int s = c_src[j];
        float b = bedge[(size_t)j * HD + h];
        float2 vv = __half22float2(*(const __half2*)&v[(size_t)s * DD + c0]);
        float a = qhs + b;
        a = a > 0.f ? a : 0.2f * a;
        float e = exp2f(a);
        den += e;
        num0 = fmaf(e, vv.x, num0);
        num1 = fmaf(e, vv.y, num1);
    }

    float inv = 1.f / (den + 1e-16f);
    float r0 = num0 * inv + bias[c0];
    float r1 = num1 * inv + bias[c0 + 1];
    if (do_elu) {
        r0 = r0 > 0.f ? r0 : expm1f(r0);
        r1 = r1 > 0.f ? r1 : expm1f(r1);
    }
    *(float2*)&out[(size_t)n * DD + c0] = make_float2(r0, r1);
}

// ---------------------------------------------------------------------------
extern "C" void kernel_launch(void* const* d_in, const int* in_sizes, int n_in,
                              void* d_out, int out_size, void* d_ws, size_t ws_size,
                              hipStream_t stream)
{
    const int*   entity = (const int*)d_in[0];
    const int*   eidx   = (const int*)d_in[1];
    const int*   etype  = (const int*)d_in[2];
    const float* ew     = (const float*)d_in[3];
    const float* ent    = (const float*)d_in[4];
    const float* pw     = (const float*)d_in[5];
    const float* pb     = (const float*)d_in[6];
    const float* rel    = (const float*)d_in[7];
    const float* Wq     = (const float*)d_in[8];
    const float* Wk     = (const float*)d_in[9];
    const float* Wv     = (const float*)d_in[10];
    const float* We     = (const float*)d_in[11];
    const float* gate   = (const float*)d_in[12];
    const float* cb     = (const float*)d_in[13];

    const int N = in_sizes[0];
    const int E = in_sizes[2];
    const int F = in_sizes[4] / N;     // 256
    const int R = in_sizes[7] / DD;    // 200

    const int* srcv = eidx;
    const int* dstv = eidx + E;

    float* ws = (float*)d_ws;
    size_t o = 0;
    float* xbuf    = ws + o; o += (size_t)N * DD;
    __half* vbuf   = (__half*)(ws + o); o += (size_t)N * DD / 2;   // fp16 v
    float* qs      = ws + o; o += (size_t)N * HD;
    float* ks      = ws + o; o += (size_t)N * HD;
    float* Wqh     = ws + o; o += 2 * DD * HD;
    float* Wkh     = ws + o; o += 2 * DD * HD;
    float* esum    = ws + o; o += (size_t)2 * R * HD;
    int*   deg     = (int*)(ws + o); o += N;
    int*   cursor  = (int*)(ws + o); o += N;
    int*   row_ptr = (int*)(ws + o); o += (size_t)N + 1;
    int*   blksum  = (int*)(ws + o); o += SCAN_B;
    int*   blkoff  = (int*)(ws + o); o += SCAN_B + 1;
    o = (o + 3) & ~(size_t)3;                       // 16B-align
    int4*  c_pack  = (int4*)(ws + o); o += (size_t)E * 4;
    int*   c_src   = (int*)(ws + o); o += E;
    o = (o + 3) & ~(size_t)3;
    float4* bedge  = (float4*)(ws + o); o += (size_t)E * 4;
    unsigned short* btp = (unsigned short*)(ws + o); o += 128 * 256 / 2;
    unsigned short* btv = (unsigned short*)(ws + o); o += 2 * DD * DD / 2;

    prep_kernel<<<16, 256, 0, stream>>>(Wq, Wk, We, rel, Wqh, Wkh, esum, R);
    prep_bt<<<(128 * 256 + 2 * DD * DD + 255) / 256, 256, 0, stream>>>(
        pw, Wv, btp, btv);

    // CSR build (layer-independent, built once)
    hipMemsetAsync(deg, 0, (size_t)2 * N * sizeof(int), stream);  // deg + cursor
    csr_count<<<(E + 255) / 256, 256, 0, stream>>>(dstv, deg, E);
    scan_partial<<<SCAN_B, SCAN_T, 0, stream>>>(deg, blksum, N);
    scan_blk<<<1, 64, 0, stream>>>(blksum, blkoff);
    scan_final<<<SCAN_B, SCAN_T, 0, stream>>>(deg, blkoff, row_ptr, N);
    csr_scatter<<<(E + 255) / 256, 256, 0, stream>>>(
        srcv, dstv, etype, ew, row_ptr, cursor, c_pack, c_src, E);

    const int gblk = (N + 63) / 64;
    // x0 = ent_table[entity] @ proj_w + proj_b   (MFMA, K=256, fp32 out)
    gemm_mfma<<<gblk, 256, 0, stream>>>(
        ent, entity, btp, pb, nullptr, nullptr,
        xbuf, nullptr, nullptr, nullptr, N, F);

    const int fblk = (N + 3) / 4;     // one 64-lane wave per node
    const int eblk = (E + 255) / 256;
    for (int l = 0; l < 2; ++l) {
        gemm_mfma<<<gblk, 256, 0, stream>>>(
            xbuf, nullptr, btv + (size_t)l * DD * DD, nullptr,
            Wqh + l * DD * HD, Wkh + l * DD * HD,
            nullptr, vbuf, qs, ks, N, DD);
        edge_prep<<<eblk, 256, 0, stream>>>(
            c_pack, ks, esum + (size_t)l * R * HD, gate + l * HD, bedge, E);
        fused_conv<<<fblk, 256, 0, stream>>>(
            row_ptr, c_src, (const float*)bedge, qs, vbuf, cb + l * DD,
            (l == 0) ? xbuf : (float*)d_out, N, (l == 0) ? 1 : 0);
    }
}

// Round 25
// 224.154 us; speedup vs baseline: 1.2093x; 1.0118x over previous
//
#include <hip/hip_runtime.h>
#include <hip/hip_fp16.h>

#define HD 4      // heads
#define DD 128    // model dim
#define CC 32     // channels per head
#define SCAN_B 64
#define SCAN_T 256

typedef float  f32x4   __attribute__((ext_vector_type(4)));
typedef short  short8v __attribute__((ext_vector_type(8)));

__device__ __forceinline__ unsigned short f2bf(float x) {
    unsigned u = __float_as_uint(x);
    return (unsigned short)((u + 0x7FFFu + ((u >> 16) & 1u)) >> 16);
}
__device__ __forceinline__ float bf2f(unsigned short h) {
    return __uint_as_float((unsigned)h << 16);
}

// ---------------------------------------------------------------------------
// Precompute per-head weight column-sums and per-relation esum table.
// ---------------------------------------------------------------------------
__global__ __launch_bounds__(256) void prep_kernel(
    const float* __restrict__ Wq, const float* __restrict__ Wk,
    const float* __restrict__ We, const float* __restrict__ rel,
    float* __restrict__ Wqh, float* __restrict__ Wkh,
    float* __restrict__ esum, int R)
{
    __shared__ float WehS[2][DD][HD];   // 4 KB
    int tid = threadIdx.x;
    for (int i = tid; i < 2 * DD * HD; i += 256) {
        int l = i / (DD * HD);
        int d = (i / HD) % DD;
        int h = i % HD;
        const float* bq = Wq + ((size_t)l * DD + d) * DD + h * CC;
        const float* bk = Wk + ((size_t)l * DD + d) * DD + h * CC;
        const float* be = We + ((size_t)l * DD + d) * DD + h * CC;
        float sq = 0.f, sk = 0.f, se = 0.f;
        for (int c = 0; c < CC; ++c) { sq += bq[c]; sk += bk[c]; se += be[c]; }
        if (blockIdx.x == 0) { Wqh[i] = sq; Wkh[i] = sk; }
        WehS[l][d][h] = se;
    }
    __syncthreads();
    for (int i = blockIdx.x * 256 + tid; i < 2 * R * HD; i += gridDim.x * 256) {
        int l = i / (R * HD);
        int r = (i / HD) % R;
        int h = i % HD;
        const float* rp = rel + (size_t)r * DD;
        float a = 0.f;
        for (int d = 0; d < DD; ++d) a += rp[d] * WehS[l][d][h];
        esum[i] = a;
    }
}

// ---------------------------------------------------------------------------
// Transposed bf16 (hi-only) weight tables.
// ---------------------------------------------------------------------------
__global__ __launch_bounds__(256) void prep_bt(
    const float* __restrict__ pw, const float* __restrict__ Wv,
    unsigned short* __restrict__ btp, unsigned short* __restrict__ btv)
{
    int t = blockIdx.x * 256 + threadIdx.x;
    if (t < 128 * 256) {
        int col = t >> 8, k = t & 255;
        btp[(size_t)col * 256 + k] = f2bf(pw[(size_t)k * DD + col]);
    } else if (t < 128 * 256 + 2 * DD * DD) {
        int u = t - 128 * 256;
        int l = u >> 14;
        int r = u & 16383;
        int col = r >> 7, k = r & 127;
        btv[((size_t)l * DD + col) * DD + k] = f2bf(Wv[((size_t)l * DD + k) * DD + col]);
    }
}

// ---------------------------------------------------------------------------
// bf16 MFMA GEMM, BK=128 chunks, one staging phase per chunk.
// A rounded to bf16 (single pass — A-lo dropped r25 for occupancy: LDS
// 68->52 KB => 3 blocks/CU). qs/ks still from exact fp32 A.
// ---------------------------------------------------------------------------
__global__ __launch_bounds__(256) void gemm_mfma(
    const float* __restrict__ A, const int* __restrict__ gather,
    const unsigned short* __restrict__ bth, const float* __restrict__ bias,
    const float* __restrict__ Wqh, const float* __restrict__ Wkh,
    float* __restrict__ Cf, __half* __restrict__ Chf,
    float* __restrict__ qs, float* __restrict__ ks,
    int M, int K)
{
    __shared__ unsigned short AhL[4][4][64][8];   // 16 KB
    __shared__ unsigned short BhL[4][8][64][8];   // 32 KB
    __shared__ float wq[DD * HD], wk[DD * HD];    // 4 KB

    const int tid = threadIdx.x;
    const int wave = tid >> 6, lane = tid & 63;
    const int row0 = blockIdx.x * 64;

    if (qs) {
        for (int i = tid; i < DD * HD; i += 256) { wq[i] = Wqh[i]; wk[i] = Wkh[i]; }
    }

    const int sr = tid >> 2;       // 0..63
    const int sks = tid & 3;       // 0..3
    int arow = row0 + sr; if (arow >= M) arow = M - 1;
    const int ga = gather ? gather[arow] : arow;
    const float* Ap = A + (size_t)ga * K + sks * 32;

    const int bc = tid >> 1;       // 0..127
    const int bh2 = (tid & 1) * 64;
    const unsigned short* Bp = bth + (size_t)bc * K + bh2;
    const int bct = bc >> 4, bfr = bc & 15;

    const int fr = lane & 15, fg = lane >> 4;

    f32x4 acc[8] = {};
    float qp[4] = {}, kp[4] = {};

    const int nch = K >> 7;        // 128-wide chunks
    for (int ch = 0; ch < nch; ++ch) {
        float4 a[8];
#pragma unroll
        for (int i = 0; i < 8; ++i) a[i] = *(const float4*)(Ap + ch * 128 + i * 4);
        short8v b[8];
#pragma unroll
        for (int i = 0; i < 8; ++i) b[i] = *(const short8v*)(Bp + ch * 128 + i * 8);

        if (ch) __syncthreads();

        {
            const int rt = sr >> 4, frr = sr & 15;
#pragma unroll
            for (int g = 0; g < 4; ++g) {
                float vv[8] = {a[g*2].x, a[g*2].y, a[g*2].z, a[g*2].w,
                               a[g*2+1].x, a[g*2+1].y, a[g*2+1].z, a[g*2+1].w};
                short8v hv;
#pragma unroll
                for (int j = 0; j < 8; ++j) hv[j] = (short)f2bf(vv[j]);
                *(short8v*)&AhL[rt][sks][g * 16 + frr][0] = hv;
            }
        }
        if (qs) {
#pragma unroll
            for (int i = 0; i < 8; ++i) {
                const float arr[4] = {a[i].x, a[i].y, a[i].z, a[i].w};
#pragma unroll
                for (int j = 0; j < 4; ++j) {
                    int d = ch * 128 + sks * 32 + i * 4 + j;
                    float4 qw = *(const float4*)&wq[d * HD];
                    float4 kw = *(const float4*)&wk[d * HD];
                    qp[0] += arr[j] * qw.x; qp[1] += arr[j] * qw.y;
                    qp[2] += arr[j] * qw.z; qp[3] += arr[j] * qw.w;
                    kp[0] += arr[j] * kw.x; kp[1] += arr[j] * kw.y;
                    kp[2] += arr[j] * kw.z; kp[3] += arr[j] * kw.w;
                }
            }
        }
#pragma unroll
        for (int g = 0; g < 8; ++g) {
            int kk = bh2 + g * 8;
            int ksb = kk >> 5, fgb = (kk & 31) >> 3;
            *(short8v*)&BhL[ksb][bct][fgb * 16 + bfr][0] = b[g];
        }
        __syncthreads();

#pragma unroll
        for (int ksc = 0; ksc < 4; ++ksc) {
            short8v ah = *(const short8v*)&AhL[wave][ksc][lane][0];
#pragma unroll
            for (int c = 0; c < 8; ++c) {
                short8v bh = *(const short8v*)&BhL[ksc][c][lane][0];
                acc[c] = __builtin_amdgcn_mfma_f32_16x16x32_bf16(ah, bh, acc[c], 0, 0, 0);
            }
        }
    }

    if (qs) {
#pragma unroll
        for (int off = 1; off < 4; off <<= 1) {
#pragma unroll
            for (int h = 0; h < 4; ++h) {
                qp[h] += __shfl_xor(qp[h], off, 64);
                kp[h] += __shfl_xor(kp[h], off, 64);
            }
        }
        if ((tid & 3) == 0) {
            int row = row0 + sr;
            if (row < M) {
                *(float4*)&qs[(size_t)row * HD] = make_float4(qp[0], qp[1], qp[2], qp[3]);
                *(float4*)&ks[(size_t)row * HD] = make_float4(kp[0], kp[1], kp[2], kp[3]);
            }
        }
    }

#pragma unroll
    for (int c = 0; c < 8; ++c) {
        float bv = bias ? bias[c * 16 + fr] : 0.f;
#pragma unroll
        for (int i = 0; i < 4; ++i) {
            int row = row0 + wave * 16 + fg * 4 + i;
            if (row < M) {
                float val = acc[c][i] + bv;
                if (Chf) Chf[(size_t)row * DD + c * 16 + fr] = __float2half(val);
                else     Cf [(size_t)row * DD + c * 16 + fr] = val;
            }
        }
    }
}

// ---------------------------------------------------------------------------
// CSR build: histogram + hierarchical 3-kernel scan + packed scatter.
// ---------------------------------------------------------------------------
__global__ __launch_bounds__(256) void csr_count(
    const int* __restrict__ dstv, int* __restrict__ deg, int E)
{
    int t = blockIdx.x * 256 + threadIdx.x;
    if (t < E) atomicAdd(&deg[dstv[t]], 1);
}

__global__ __launch_bounds__(SCAN_T) void scan_partial(
    const int* __restrict__ deg, int* __restrict__ blksum, int N)
{
    __shared__ int red[SCAN_T];
    int chunk = (N + SCAN_B - 1) / SCAN_B;
    int b0 = blockIdx.x * chunk;
    int e0 = b0 + chunk; if (e0 > N) e0 = N;
    int s = 0;
    for (int i = b0 + threadIdx.x; i < e0; i += SCAN_T) s += deg[i];
    red[threadIdx.x] = s;
    __syncthreads();
    for (int off = SCAN_T / 2; off > 0; off >>= 1) {
        if (threadIdx.x < off) red[threadIdx.x] += red[threadIdx.x + off];
        __syncthreads();
    }
    if (threadIdx.x == 0) blksum[blockIdx.x] = red[0];
}

__global__ __launch_bounds__(64) void scan_blk(
    const int* __restrict__ blksum, int* __restrict__ blkoff)
{
    if (threadIdx.x == 0) {
        int acc = 0;
        for (int i = 0; i < SCAN_B; ++i) { blkoff[i] = acc; acc += blksum[i]; }
        blkoff[SCAN_B] = acc;
    }
}

__global__ __launch_bounds__(SCAN_T) void scan_final(
    const int* __restrict__ deg, const int* __restrict__ blkoff,
    int* __restrict__ row_ptr, int N)
{
    __shared__ int tsum[SCAN_T];
    int tid = threadIdx.x;
    int chunk = (N + SCAN_B - 1) / SCAN_B;
    int b0 = blockIdx.x * chunk;
    int e0 = b0 + chunk; if (e0 > N) e0 = N;
    int tchunk = (chunk + SCAN_T - 1) / SCAN_T;
    int tb = b0 + tid * tchunk;
    int te = tb + tchunk; if (te > e0) te = e0;
    int s = 0;
    for (int i = tb; i < te; ++i) s += deg[i];
    tsum[tid] = s;
    __syncthreads();
    for (int off = 1; off < SCAN_T; off <<= 1) {
        int v = (tid >= off) ? tsum[tid - off] : 0;
        __syncthreads();
        tsum[tid] += v;
        __syncthreads();
    }
    int base = blkoff[blockIdx.x] + ((tid == 0) ? 0 : tsum[tid - 1]);
    for (int i = tb; i < te; ++i) { row_ptr[i] = base; base += deg[i]; }
    if (blockIdx.x == SCAN_B - 1 && tid == SCAN_T - 1) row_ptr[N] = blkoff[SCAN_B];
}

__global__ __launch_bounds__(256) void csr_scatter(
    const int* __restrict__ srcv, const int* __restrict__ dstv,
    const int* __restrict__ etype, const float* __restrict__ ew,
    const int* __restrict__ row_ptr, int* __restrict__ cursor,
    int4* __restrict__ c_pack, int* __restrict__ c_src, int E)
{
    int e = blockIdx.x * 256 + threadIdx.x;
    if (e >= E) return;
    int d = dstv[e];
    int p = row_ptr[d] + atomicAdd(&cursor[d], 1);
    c_pack[p] = make_int4(srcv[e], etype[e], __float_as_int(ew[e]), 0);
    c_src[p] = srcv[e];
}

// ---------------------------------------------------------------------------
// Per-layer edge precompute: bedge[e][h] = (ks[src][h]+esum[et][h])*scL
//                                          + gate[h]*log2e*w.
// ---------------------------------------------------------------------------
__global__ __launch_bounds__(256) void edge_prep(
    const int4* __restrict__ c_pack, const float* __restrict__ ks,
    const float* __restrict__ esum, const float* __restrict__ gate,
    float4* __restrict__ bedge, int E)
{
    int t = blockIdx.x * 256 + threadIdx.x;
    if (t >= E) return;
    const float L2E = 1.4426950408889634f;
    const float scL = 0.17677669529663687f * 1.4426950408889634f;
    int4 p = c_pack[t];
    float w = __int_as_float(p.z);
    float4 kv = *(const float4*)&ks[(size_t)p.x * HD];
    float4 ev = *(const float4*)&esum[(size_t)p.y * HD];
    float4 g  = *(const float4*)gate;
    float4 b;
    b.x = (kv.x + ev.x) * scL + g.x * L2E * w;
    b.y = (kv.y + ev.y) * scL + g.y * L2E * w;
    b.z = (kv.z + ev.z) * scL + g.z * L2E * w;
    b.w = (kv.w + ev.w) * scL + g.w * L2E * w;
    bedge[t] = b;
}

// ---------------------------------------------------------------------------
// Fused per-layer softmax+aggregate+epilogue. One wave per dst node.
// ---------------------------------------------------------------------------
__global__ __launch_bounds__(256) void fused_conv(
    const int* __restrict__ row_ptr, const int* __restrict__ c_src,
    const float* __restrict__ bedge, const float* __restrict__ qs,
    const __half* __restrict__ v, const float* __restrict__ bias,
    float* __restrict__ out, int N, int do_elu)
{
    int gw = (blockIdx.x * 256 + threadIdx.x) >> 6;   // global wave id = node
    int lane = threadIdx.x & 63;
    if (gw >= N) return;
    const int n = gw;
    const int beg = row_ptr[n], end = row_ptr[n + 1];
    const int c0 = lane * 2;
    const int h = lane >> 4;
    const float scL = 0.17677669529663687f * 1.4426950408889634f;
    const float qhs = qs[(size_t)n * HD + h] * scL;

    float num0 = 0.f, num1 = 0.f, den = 0.f;

    int j = beg;
    for (; j + 8 <= end; j += 8) {
        int s[8]; float bh[8]; float2 vv[8];
#pragma unroll
        for (int u = 0; u < 8; ++u) s[u] = c_src[j + u];
#pragma unroll
        for (int u = 0; u < 8; ++u) bh[u] = bedge[(size_t)(j + u) * HD + h];
#pragma unroll
        for (int u = 0; u < 8; ++u)
            vv[u] = __half22float2(*(const __half2*)&v[(size_t)s[u] * DD + c0]);
#pragma unroll
        for (int u = 0; u < 8; ++u) {
            float a = qhs + bh[u];
            a = a > 0.f ? a : 0.2f * a;
            float e = exp2f(a);
            den += e;
            num0 = fmaf(e, vv[u].x, num0);
            num1 = fmaf(e, vv[u].y, num1);
        }
    }
    for (; j + 4 <= end; j += 4) {
        int s0 = c_src[j], s1 = c_src[j + 1], s2 = c_src[j + 2], s3 = c_src[j + 3];
        float b0 = bedge[(size_t)j * HD + h];
        float b1 = bedge[(size_t)(j + 1) * HD + h];
        float b2 = bedge[(size_t)(j + 2) * HD + h];
        float b3 = bedge[(size_t)(j + 3) * HD + h];
        float2 vv0 = __half22float2(*(const __half2*)&v[(size_t)s0 * DD + c0]);
        float2 vv1 = __half22float2(*(const __half2*)&v[(size_t)s1 * DD + c0]);
        float2 vv2 = __half22float2(*(const __half2*)&v[(size_t)s2 * DD + c0]);
        float2 vv3 = __half22float2(*(const __half2*)&v[(size_t)s3 * DD + c0]);
        float a0 = qhs + b0, a1 = qhs + b1, a2 = qhs + b2, a3 = qhs + b3;
        a0 = a0 > 0.f ? a0 : 0.2f * a0;
        a1 = a1 > 0.f ? a1 : 0.2f * a1;
        a2 = a2 > 0.f ? a2 : 0.2f * a2;
        a3 = a3 > 0.f ? a3 : 0.2f * a3;
        float e0 = exp2f(a0), e1 = exp2f(a1);
        float e2 = exp2f(a2), e3 = exp2f(a3);
        den += (e0 + e1) + (e2 + e3);
        num0 = fmaf(e0, vv0.x, num0); num1 = fmaf(e0, vv0.y, num1);
        num0 = fmaf(e1, vv1.x, num0); num1 = fmaf(e1, vv1.y, num1);
        num0 = fmaf(e2, vv2.x, num0); num1 = fmaf(e2, vv2.y, num1);
        num0 = fmaf(e3, vv3.x, num0); num1 = fmaf(e3, vv3.y, num1);
    }
    for (; j < end; ++j) {
        int s = c_src[j];
        float b = bedge[(size_t)j * HD + h];
        float2 vv = __half22float2(*(const __half2*)&v[(size_t)s * DD + c0]);
        float a = qhs + b;
        a = a > 0.f ? a : 0.2f * a;
        float e = exp2f(a);
        den += e;
        num0 = fmaf(e, vv.x, num0);
        num1 = fmaf(e, vv.y, num1);
    }

    float inv = 1.f / (den + 1e-16f);
    float r0 = num0 * inv + bias[c0];
    float r1 = num1 * inv + bias[c0 + 1];
    if (do_elu) {
        r0 = r0 > 0.f ? r0 : expm1f(r0);
        r1 = r1 > 0.f ? r1 : expm1f(r1);
    }
    *(float2*)&out[(size_t)n * DD + c0] = make_float2(r0, r1);
}

// ---------------------------------------------------------------------------
extern "C" void kernel_launch(void* const* d_in, const int* in_sizes, int n_in,
                              void* d_out, int out_size, void* d_ws, size_t ws_size,
                              hipStream_t stream)
{
    const int*   entity = (const int*)d_in[0];
    const int*   eidx   = (const int*)d_in[1];
    const int*   etype  = (const int*)d_in[2];
    const float* ew     = (const float*)d_in[3];
    const float* ent    = (const float*)d_in[4];
    const float* pw     = (const float*)d_in[5];
    const float* pb     = (const float*)d_in[6];
    const float* rel    = (const float*)d_in[7];
    const float* Wq     = (const float*)d_in[8];
    const float* Wk     = (const float*)d_in[9];
    const float* Wv     = (const float*)d_in[10];
    const float* We     = (const float*)d_in[11];
    const float* gate   = (const float*)d_in[12];
    const float* cb     = (const float*)d_in[13];

    const int N = in_sizes[0];
    const int E = in_sizes[2];
    const int F = in_sizes[4] / N;     // 256
    const int R = in_sizes[7] / DD;    // 200

    const int* srcv = eidx;
    const int* dstv = eidx + E;

    float* ws = (float*)d_ws;
    size_t o = 0;
    float* xbuf    = ws + o; o += (size_t)N * DD;
    __half* vbuf   = (__half*)(ws + o); o += (size_t)N * DD / 2;   // fp16 v
    float* qs      = ws + o; o += (size_t)N * HD;
    float* ks      = ws + o; o += (size_t)N * HD;
    float* Wqh     = ws + o; o += 2 * DD * HD;
    float* Wkh     = ws + o; o += 2 * DD * HD;
    float* esum    = ws + o; o += (size_t)2 * R * HD;
    int*   deg     = (int*)(ws + o); o += N;
    int*   cursor  = (int*)(ws + o); o += N;
    int*   row_ptr = (int*)(ws + o); o += (size_t)N + 1;
    int*   blksum  = (int*)(ws + o); o += SCAN_B;
    int*   blkoff  = (int*)(ws + o); o += SCAN_B + 1;
    o = (o + 3) & ~(size_t)3;                       // 16B-align
    int4*  c_pack  = (int4*)(ws + o); o += (size_t)E * 4;
    int*   c_src   = (int*)(ws + o); o += E;
    o = (o + 3) & ~(size_t)3;
    float4* bedge  = (float4*)(ws + o); o += (size_t)E * 4;
    unsigned short* btp = (unsigned short*)(ws + o); o += 128 * 256 / 2;
    unsigned short* btv = (unsigned short*)(ws + o); o += 2 * DD * DD / 2;

    prep_kernel<<<16, 256, 0, stream>>>(Wq, Wk, We, rel, Wqh, Wkh, esum, R);
    prep_bt<<<(128 * 256 + 2 * DD * DD + 255) / 256, 256, 0, stream>>>(
        pw, Wv, btp, btv);

    // CSR build (layer-independent, built once)
    hipMemsetAsync(deg, 0, (size_t)2 * N * sizeof(int), stream);  // deg + cursor
    csr_count<<<(E + 255) / 256, 256, 0, stream>>>(dstv, deg, E);
    scan_partial<<<SCAN_B, SCAN_T, 0, stream>>>(deg, blksum, N);
    scan_blk<<<1, 64, 0, stream>>>(blksum, blkoff);
    scan_final<<<SCAN_B, SCAN_T, 0, stream>>>(deg, blkoff, row_ptr, N);
    csr_scatter<<<(E + 255) / 256, 256, 0, stream>>>(
        srcv, dstv, etype, ew, row_ptr, cursor, c_pack, c_src, E);

    const int gblk = (N + 63) / 64;
    // x0 = ent_table[entity] @ proj_w + proj_b   (MFMA, K=256, fp32 out)
    gemm_mfma<<<gblk, 256, 0, stream>>>(
        ent, entity, btp, pb, nullptr, nullptr,
        xbuf, nullptr, nullptr, nullptr, N, F);

    const int fblk = (N + 3) / 4;     // one 64-lane wave per node
    const int eblk = (E + 255) / 256;
    for (int l = 0; l < 2; ++l) {
        gemm_mfma<<<gblk, 256, 0, stream>>>(
            xbuf, nullptr, btv + (size_t)l * DD * DD, nullptr,
            Wqh + l * DD * HD, Wkh + l * DD * HD,
            nullptr, vbuf, qs, ks, N, DD);
        edge_prep<<<eblk, 256, 0, stream>>>(
            c_pack, ks, esum + (size_t)l * R * HD, gate + l * HD, bedge, E);
        fused_conv<<<fblk, 256, 0, stream>>>(
            row_ptr, c_src, (const float*)bedge, qs, vbuf, cb + l * DD,
            (l == 0) ? xbuf : (float*)d_out, N, (l == 0) ? 1 : 0);
    }
}